// Round 1
// baseline (638.918 us; speedup 1.0000x reference)
//
#include <hip/hip_runtime.h>

// ---------------------------------------------------------------------------
// GCN 2-layer: out = A_norm * relu(A_norm*(X@W1)+b1) @ W2 + b2
// A_norm = D^-1/2 (A + I) D^-1/2, deg from destination (col) incl. self-loop.
//
// Decomposition (per layer):
//   hs[i]  = dinv[i] * (X@W)[i]          (pre-scale in GEMM epilogue)
//   agg[c] = hs[c] + sum_{e: col=c} hs[row_e]   (init=self-loop, atomics)
//   next-layer input row = f(dinv[c]*agg[c] + b)  (post-scale fused downstream)
// ---------------------------------------------------------------------------

__global__ __launch_bounds__(256) void k_init_deg(float* __restrict__ deg, int n) {
    int i = blockIdx.x * 256 + threadIdx.x;
    if (i < n) deg[i] = 1.0f;   // self-loop
}

__global__ __launch_bounds__(256) void k_deg(const int* __restrict__ col,
                                             float* __restrict__ deg, int e) {
    int i = blockIdx.x * 256 + threadIdx.x;
    if (i < e) atomicAdd(&deg[col[i]], 1.0f);
}

__global__ __launch_bounds__(256) void k_rsqrt(float* __restrict__ deg, int n) {
    int i = blockIdx.x * 256 + threadIdx.x;
    if (i < n) deg[i] = rsqrtf(deg[i]);
}

// GEMM1: hs = (X @ W1) * dinv[i]; agg initialized to hs (self-loop term).
// X: [n,128], W1: [128,128]. Block: 64 rows, 256 threads, thread = 4r x 8c.
__global__ __launch_bounds__(256) void k_gemm1(const float* __restrict__ x,
                                               const float* __restrict__ W,
                                               const float* __restrict__ dinv,
                                               float* __restrict__ hs,
                                               float* __restrict__ agg, int n) {
    __shared__ float Ws[128 * 128];
    __shared__ float Xs[64 * 132];   // +4 pad breaks bank aliasing on broadcasts
    int t = threadIdx.x;

    const float4* Wv = (const float4*)W;
    float4* Wsv = (float4*)Ws;
#pragma unroll
    for (int i = 0; i < 16; ++i) Wsv[t + i * 256] = Wv[t + i * 256];

    int r0blk = blockIdx.x * 64;
    const float4* Xv = (const float4*)x;
#pragma unroll
    for (int i = 0; i < 8; ++i) {
        int idx = t + i * 256;           // 0..2047 float4s
        int r = idx >> 5;                // 32 float4 per row
        int kq = idx & 31;
        float4 v = make_float4(0.f, 0.f, 0.f, 0.f);
        int gr = r0blk + r;
        if (gr < n) v = Xv[gr * 32 + kq];
        *(float4*)&Xs[r * 132 + kq * 4] = v;
    }
    __syncthreads();

    int tx = t & 15, ty = t >> 4;
    int j0 = tx * 8, r0 = ty * 4;
    float acc[4][8];
#pragma unroll
    for (int a = 0; a < 4; ++a)
#pragma unroll
        for (int b = 0; b < 8; ++b) acc[a][b] = 0.f;

#pragma unroll 4
    for (int k = 0; k < 128; ++k) {
        float xv[4];
#pragma unroll
        for (int a = 0; a < 4; ++a) xv[a] = Xs[(r0 + a) * 132 + k];
        float4 wa = *(const float4*)&Ws[k * 128 + j0];
        float4 wb = *(const float4*)&Ws[k * 128 + j0 + 4];
        float w[8] = {wa.x, wa.y, wa.z, wa.w, wb.x, wb.y, wb.z, wb.w};
#pragma unroll
        for (int a = 0; a < 4; ++a)
#pragma unroll
            for (int b = 0; b < 8; ++b) acc[a][b] += xv[a] * w[b];
    }

#pragma unroll
    for (int a = 0; a < 4; ++a) {
        int gr = r0blk + r0 + a;
        if (gr < n) {
            float d = dinv[gr];
            float4 o0 = make_float4(acc[a][0] * d, acc[a][1] * d, acc[a][2] * d, acc[a][3] * d);
            float4 o1 = make_float4(acc[a][4] * d, acc[a][5] * d, acc[a][6] * d, acc[a][7] * d);
            *(float4*)&hs[gr * 128 + j0]      = o0;
            *(float4*)&hs[gr * 128 + j0 + 4]  = o1;
            *(float4*)&agg[gr * 128 + j0]     = o0;
            *(float4*)&agg[gr * 128 + j0 + 4] = o1;
        }
    }
}

// Edge aggregation layer 1: one wave per edge, 128 channels (2 per lane).
__global__ __launch_bounds__(256) void k_edge1(const int* __restrict__ row,
                                               const int* __restrict__ col,
                                               const float* __restrict__ hs,
                                               float* __restrict__ agg, int e) {
    int wid = (blockIdx.x * 256 + threadIdx.x) >> 6;
    if (wid >= e) return;
    int lane = threadIdx.x & 63;
    int r = row[wid], c = col[wid];
    float v0 = hs[r * 128 + lane];
    float v1 = hs[r * 128 + 64 + lane];
    atomicAdd(&agg[c * 128 + lane], v0);
    atomicAdd(&agg[c * 128 + 64 + lane], v1);
}

// GEMM2: input row = relu(dinv[i]*agg1[i] + b1)  (fused while staging to LDS)
// output: ps2 = dinv[i] * (H2 @ W2), written to scratch AND d_out (self-loop).
__global__ __launch_bounds__(256) void k_gemm2(const float* __restrict__ agg1,
                                               const float* __restrict__ W2,
                                               const float* __restrict__ b1,
                                               const float* __restrict__ dinv,
                                               float* __restrict__ ps2,
                                               float* __restrict__ out, int n) {
    __shared__ float Ws[128 * 64];
    __shared__ float Xs[64 * 132];
    int t = threadIdx.x;

    const float4* Wv = (const float4*)W2;
    float4* Wsv = (float4*)Ws;
#pragma unroll
    for (int i = 0; i < 8; ++i) Wsv[t + i * 256] = Wv[t + i * 256];

    int r0blk = blockIdx.x * 64;
    const float4* Av = (const float4*)agg1;
    const float4* Bv = (const float4*)b1;
#pragma unroll
    for (int i = 0; i < 8; ++i) {
        int idx = t + i * 256;
        int r = idx >> 5;
        int kq = idx & 31;
        float4 v = make_float4(0.f, 0.f, 0.f, 0.f);
        int gr = r0blk + r;
        if (gr < n) {
            float4 a4 = Av[gr * 32 + kq];
            float d = dinv[gr];
            float4 bb = Bv[kq];
            v.x = fmaxf(a4.x * d + bb.x, 0.f);
            v.y = fmaxf(a4.y * d + bb.y, 0.f);
            v.z = fmaxf(a4.z * d + bb.z, 0.f);
            v.w = fmaxf(a4.w * d + bb.w, 0.f);
        }
        *(float4*)&Xs[r * 132 + kq * 4] = v;
    }
    __syncthreads();

    int tx = t & 15, ty = t >> 4;
    int j0 = tx * 4, r0 = ty * 4;
    float acc[4][4];
#pragma unroll
    for (int a = 0; a < 4; ++a)
#pragma unroll
        for (int b = 0; b < 4; ++b) acc[a][b] = 0.f;

#pragma unroll 4
    for (int k = 0; k < 128; ++k) {
        float xv[4];
#pragma unroll
        for (int a = 0; a < 4; ++a) xv[a] = Xs[(r0 + a) * 132 + k];
        float4 w = *(const float4*)&Ws[k * 64 + j0];
#pragma unroll
        for (int a = 0; a < 4; ++a) {
            acc[a][0] += xv[a] * w.x;
            acc[a][1] += xv[a] * w.y;
            acc[a][2] += xv[a] * w.z;
            acc[a][3] += xv[a] * w.w;
        }
    }

#pragma unroll
    for (int a = 0; a < 4; ++a) {
        int gr = r0blk + r0 + a;
        if (gr < n) {
            float d = dinv[gr];
            float4 o = make_float4(acc[a][0] * d, acc[a][1] * d, acc[a][2] * d, acc[a][3] * d);
            *(float4*)&ps2[gr * 64 + j0] = o;
            *(float4*)&out[gr * 64 + j0] = o;
        }
    }
}

// Edge aggregation layer 2: one wave per edge, 64 channels (1 per lane).
__global__ __launch_bounds__(256) void k_edge2(const int* __restrict__ row,
                                               const int* __restrict__ col,
                                               const float* __restrict__ ps2,
                                               float* __restrict__ out, int e) {
    int wid = (blockIdx.x * 256 + threadIdx.x) >> 6;
    if (wid >= e) return;
    int lane = threadIdx.x & 63;
    int r = row[wid], c = col[wid];
    atomicAdd(&out[c * 64 + lane], ps2[r * 64 + lane]);
}

// Final: out = out * dinv[row] + b2  (vectorized float4, in place)
__global__ __launch_bounds__(256) void k_final(float* __restrict__ out,
                                               const float* __restrict__ dinv,
                                               const float* __restrict__ b2, int n) {
    int idx = blockIdx.x * 256 + threadIdx.x;   // over n*16 float4
    if (idx >= n * 16) return;
    int r = idx >> 4;
    int q = idx & 15;
    float4 v = ((float4*)out)[idx];
    float d = dinv[r];
    float4 bb = ((const float4*)b2)[q];
    v.x = v.x * d + bb.x;
    v.y = v.y * d + bb.y;
    v.z = v.z * d + bb.z;
    v.w = v.w * d + bb.w;
    ((float4*)out)[idx] = v;
}

extern "C" void kernel_launch(void* const* d_in, const int* in_sizes, int n_in,
                              void* d_out, int out_size, void* d_ws, size_t ws_size,
                              hipStream_t stream) {
    const float* x  = (const float*)d_in[0];
    const int*   ei = (const int*)d_in[1];
    const float* W1 = (const float*)d_in[2];
    const float* b1 = (const float*)d_in[3];
    const float* W2 = (const float*)d_in[4];
    const float* b2 = (const float*)d_in[5];
    float* out = (float*)d_out;

    int n = in_sizes[0] / 128;       // 50000
    int e = in_sizes[1] / 2;         // 800000
    const int* row = ei;             // sources
    const int* col = ei + e;         // destinations

    float* w    = (float*)d_ws;
    float* deg  = w;                         // n floats (becomes dinv in place)
    float* hs1  = w + ((n + 3) & ~3);        // n*128
    float* agg1 = hs1 + n * 128;             // n*128
    float* ps2  = hs1;                       // reuse hs1 (free after k_edge1)

    int nb = (n + 255) / 256;
    k_init_deg<<<nb, 256, 0, stream>>>(deg, n);
    k_deg<<<(e + 255) / 256, 256, 0, stream>>>(col, deg, e);
    k_rsqrt<<<nb, 256, 0, stream>>>(deg, n);

    k_gemm1<<<(n + 63) / 64, 256, 0, stream>>>(x, W1, deg, hs1, agg1, n);
    k_edge1<<<(e * 64 + 255) / 256, 256, 0, stream>>>(row, col, hs1, agg1, e);

    k_gemm2<<<(n + 63) / 64, 256, 0, stream>>>(agg1, W2, b1, deg, ps2, out, n);
    k_edge2<<<(e * 64 + 255) / 256, 256, 0, stream>>>(row, col, ps2, out, e);

    k_final<<<(n * 16 + 255) / 256, 256, 0, stream>>>(out, deg, b2, n);
}

// Round 2
// 297.638 us; speedup vs baseline: 2.1466x; 2.1466x over previous
//
#include <hip/hip_runtime.h>

// ---------------------------------------------------------------------------
// GCN 2-layer: out = A_norm * relu(A_norm*(X@W1)+b1) @ W2 + b2
// A_norm = D^-1/2 (A + I) D^-1/2.
//
// Round-2 structure: build CSR-by-destination (counting sort), then
// gather-based segmented sums (no float atomics, single write per output row).
//   hs  = dinv * (X@W1)                      [gemm1]
//   h1[c] = relu(dinv[c]*(hs[c]+sum hs[src]) + b1)   [gather1]
//   ps2 = dinv * (h1@W2)                     [gemm2]
//   out[c] = dinv[c]*(ps2[c]+sum ps2[src]) + b2      [gather2]
// ---------------------------------------------------------------------------

__global__ __launch_bounds__(256) void k_zero(int* __restrict__ cnt, int n) {
    int i = blockIdx.x * 256 + threadIdx.x;
    if (i < n) cnt[i] = 0;
}

__global__ __launch_bounds__(256) void k_hist(const int* __restrict__ col,
                                              int* __restrict__ cnt, int e) {
    int i = blockIdx.x * 256 + threadIdx.x;
    if (i < e) atomicAdd(&cnt[col[i]], 1);
}

// Per-block exclusive scan (256 elems/block); excl written to indptr, block sums out.
__global__ __launch_bounds__(256) void k_scan1(const int* __restrict__ cnt,
                                               int* __restrict__ indptr,
                                               int* __restrict__ bsum, int n) {
    __shared__ int s[256];
    int t = threadIdx.x;
    int i = blockIdx.x * 256 + t;
    int v = (i < n) ? cnt[i] : 0;
    s[t] = v;
    __syncthreads();
#pragma unroll
    for (int off = 1; off < 256; off <<= 1) {
        int u = (t >= off) ? s[t - off] : 0;
        __syncthreads();
        s[t] += u;
        __syncthreads();
    }
    if (i < n) indptr[i] = s[t] - v;           // exclusive-in-block
    if (t == 255) bsum[blockIdx.x] = s[255];   // block total
}

// Single-block exclusive scan of block sums (requires nb <= 256; n<=65536).
__global__ __launch_bounds__(256) void k_scan2(int* __restrict__ bsum, int nb) {
    __shared__ int s[256];
    int t = threadIdx.x;
    int v = (t < nb) ? bsum[t] : 0;
    s[t] = v;
    __syncthreads();
#pragma unroll
    for (int off = 1; off < 256; off <<= 1) {
        int u = (t >= off) ? s[t - off] : 0;
        __syncthreads();
        s[t] += u;
        __syncthreads();
    }
    if (t < nb) bsum[t] = s[t] - v;            // exclusive
}

__global__ __launch_bounds__(256) void k_scan3(int* __restrict__ indptr,
                                               int* __restrict__ pos,
                                               const int* __restrict__ bsum,
                                               const int* __restrict__ cnt,
                                               float* __restrict__ dinv,
                                               int n, int e) {
    int i = blockIdx.x * 256 + threadIdx.x;
    if (i < n) {
        int v = indptr[i] + bsum[blockIdx.x];
        indptr[i] = v;
        pos[i] = v;
        dinv[i] = rsqrtf((float)cnt[i] + 1.0f);
        if (i == n - 1) indptr[n] = e;
    }
}

__global__ __launch_bounds__(256) void k_scatter(const int* __restrict__ row,
                                                 const int* __restrict__ col,
                                                 int* __restrict__ pos,
                                                 int* __restrict__ srcidx, int e) {
    int i = blockIdx.x * 256 + threadIdx.x;
    if (i < e) {
        int p = atomicAdd(&pos[col[i]], 1);
        srcidx[p] = row[i];
    }
}

// GEMM1: hs = dinv[i] * (X @ W1). X:[n,128], W1:[128,128].
__global__ __launch_bounds__(256) void k_gemm1(const float* __restrict__ x,
                                               const float* __restrict__ W,
                                               const float* __restrict__ dinv,
                                               float* __restrict__ hs, int n) {
    __shared__ float Ws[128 * 128];
    __shared__ float Xs[64 * 132];
    int t = threadIdx.x;

    const float4* Wv = (const float4*)W;
    float4* Wsv = (float4*)Ws;
#pragma unroll
    for (int i = 0; i < 16; ++i) Wsv[t + i * 256] = Wv[t + i * 256];

    int r0blk = blockIdx.x * 64;
    const float4* Xv = (const float4*)x;
#pragma unroll
    for (int i = 0; i < 8; ++i) {
        int idx = t + i * 256;
        int r = idx >> 5;
        int kq = idx & 31;
        float4 v = make_float4(0.f, 0.f, 0.f, 0.f);
        int gr = r0blk + r;
        if (gr < n) v = Xv[gr * 32 + kq];
        *(float4*)&Xs[r * 132 + kq * 4] = v;
    }
    __syncthreads();

    int tx = t & 15, ty = t >> 4;
    int j0 = tx * 8, r0 = ty * 4;
    float acc[4][8];
#pragma unroll
    for (int a = 0; a < 4; ++a)
#pragma unroll
        for (int b = 0; b < 8; ++b) acc[a][b] = 0.f;

#pragma unroll 4
    for (int k = 0; k < 128; ++k) {
        float xv[4];
#pragma unroll
        for (int a = 0; a < 4; ++a) xv[a] = Xs[(r0 + a) * 132 + k];
        float4 wa = *(const float4*)&Ws[k * 128 + j0];
        float4 wb = *(const float4*)&Ws[k * 128 + j0 + 4];
        float w[8] = {wa.x, wa.y, wa.z, wa.w, wb.x, wb.y, wb.z, wb.w};
#pragma unroll
        for (int a = 0; a < 4; ++a)
#pragma unroll
            for (int b = 0; b < 8; ++b) acc[a][b] += xv[a] * w[b];
    }

#pragma unroll
    for (int a = 0; a < 4; ++a) {
        int gr = r0blk + r0 + a;
        if (gr < n) {
            float d = dinv[gr];
            *(float4*)&hs[gr * 128 + j0] =
                make_float4(acc[a][0] * d, acc[a][1] * d, acc[a][2] * d, acc[a][3] * d);
            *(float4*)&hs[gr * 128 + j0 + 4] =
                make_float4(acc[a][4] * d, acc[a][5] * d, acc[a][6] * d, acc[a][7] * d);
        }
    }
}

// Gather1: one wave per node; 128 ch as float2/lane.
// h1[c] = relu(dinv[c]*(hs[c] + sum_{src} hs[src]) + b1)
__global__ __launch_bounds__(256) void k_gather1(const int* __restrict__ indptr,
                                                 const int* __restrict__ srcidx,
                                                 const float* __restrict__ hs,
                                                 const float* __restrict__ dinv,
                                                 const float* __restrict__ b1,
                                                 float* __restrict__ h1, int n) {
    int wid = (blockIdx.x * 256 + threadIdx.x) >> 6;
    if (wid >= n) return;
    int lane = threadIdx.x & 63;
    int beg = indptr[wid], end = indptr[wid + 1];
    const float2* hv = (const float2*)hs;
    float2 a0 = hv[wid * 64 + lane];
    float2 a1 = make_float2(0.f, 0.f);
    int j = beg;
    for (; j + 1 < end; j += 2) {
        int s0 = srcidx[j], s1 = srcidx[j + 1];
        float2 v0 = hv[s0 * 64 + lane];
        float2 v1 = hv[s1 * 64 + lane];
        a0.x += v0.x; a0.y += v0.y;
        a1.x += v1.x; a1.y += v1.y;
    }
    if (j < end) {
        int s0 = srcidx[j];
        float2 v0 = hv[s0 * 64 + lane];
        a0.x += v0.x; a0.y += v0.y;
    }
    float d = dinv[wid];
    float2 bb = ((const float2*)b1)[lane];
    float2 o;
    o.x = fmaxf((a0.x + a1.x) * d + bb.x, 0.f);
    o.y = fmaxf((a0.y + a1.y) * d + bb.y, 0.f);
    ((float2*)h1)[wid * 64 + lane] = o;
}

// GEMM2: ps2 = dinv[i] * (h1 @ W2). h1:[n,128], W2:[128,64].
__global__ __launch_bounds__(256) void k_gemm2(const float* __restrict__ h1,
                                               const float* __restrict__ W2,
                                               const float* __restrict__ dinv,
                                               float* __restrict__ ps2, int n) {
    __shared__ float Ws[128 * 64];
    __shared__ float Xs[64 * 132];
    int t = threadIdx.x;

    const float4* Wv = (const float4*)W2;
    float4* Wsv = (float4*)Ws;
#pragma unroll
    for (int i = 0; i < 8; ++i) Wsv[t + i * 256] = Wv[t + i * 256];

    int r0blk = blockIdx.x * 64;
    const float4* Xv = (const float4*)h1;
#pragma unroll
    for (int i = 0; i < 8; ++i) {
        int idx = t + i * 256;
        int r = idx >> 5;
        int kq = idx & 31;
        float4 v = make_float4(0.f, 0.f, 0.f, 0.f);
        int gr = r0blk + r;
        if (gr < n) v = Xv[gr * 32 + kq];
        *(float4*)&Xs[r * 132 + kq * 4] = v;
    }
    __syncthreads();

    int tx = t & 15, ty = t >> 4;
    int j0 = tx * 4, r0 = ty * 4;
    float acc[4][4];
#pragma unroll
    for (int a = 0; a < 4; ++a)
#pragma unroll
        for (int b = 0; b < 4; ++b) acc[a][b] = 0.f;

#pragma unroll 4
    for (int k = 0; k < 128; ++k) {
        float xv[4];
#pragma unroll
        for (int a = 0; a < 4; ++a) xv[a] = Xs[(r0 + a) * 132 + k];
        float4 w = *(const float4*)&Ws[k * 64 + j0];
#pragma unroll
        for (int a = 0; a < 4; ++a) {
            acc[a][0] += xv[a] * w.x;
            acc[a][1] += xv[a] * w.y;
            acc[a][2] += xv[a] * w.z;
            acc[a][3] += xv[a] * w.w;
        }
    }

#pragma unroll
    for (int a = 0; a < 4; ++a) {
        int gr = r0blk + r0 + a;
        if (gr < n) {
            float d = dinv[gr];
            *(float4*)&ps2[gr * 64 + j0] =
                make_float4(acc[a][0] * d, acc[a][1] * d, acc[a][2] * d, acc[a][3] * d);
        }
    }
}

// Gather2: one wave per node; 64 ch, 1 float/lane.
// out[c] = dinv[c]*(ps2[c] + sum_{src} ps2[src]) + b2
__global__ __launch_bounds__(256) void k_gather2(const int* __restrict__ indptr,
                                                 const int* __restrict__ srcidx,
                                                 const float* __restrict__ ps2,
                                                 const float* __restrict__ dinv,
                                                 const float* __restrict__ b2,
                                                 float* __restrict__ out, int n) {
    int wid = (blockIdx.x * 256 + threadIdx.x) >> 6;
    if (wid >= n) return;
    int lane = threadIdx.x & 63;
    int beg = indptr[wid], end = indptr[wid + 1];
    float a0 = ps2[wid * 64 + lane];
    float a1 = 0.f;
    int j = beg;
    for (; j + 1 < end; j += 2) {
        int s0 = srcidx[j], s1 = srcidx[j + 1];
        a0 += ps2[s0 * 64 + lane];
        a1 += ps2[s1 * 64 + lane];
    }
    if (j < end) a0 += ps2[srcidx[j] * 64 + lane];
    out[wid * 64 + lane] = (a0 + a1) * dinv[wid] + b2[lane];
}

extern "C" void kernel_launch(void* const* d_in, const int* in_sizes, int n_in,
                              void* d_out, int out_size, void* d_ws, size_t ws_size,
                              hipStream_t stream) {
    const float* x  = (const float*)d_in[0];
    const int*   ei = (const int*)d_in[1];
    const float* W1 = (const float*)d_in[2];
    const float* b1 = (const float*)d_in[3];
    const float* W2 = (const float*)d_in[4];
    const float* b2 = (const float*)d_in[5];
    float* out = (float*)d_out;

    int n = in_sizes[0] / 128;       // 50000
    int e = in_sizes[1] / 2;         // 800000
    const int* row = ei;             // sources
    const int* col = ei + e;         // destinations

    // Workspace layout (element offsets kept 4-aligned for float4 use).
    int* iw = (int*)d_ws;
    int* cnt    = iw;                         // n
    int* indptr = cnt + n;                    // n+1
    int* pos    = indptr + (n + 1);           // n
    int* bsum   = pos + n;                    // 256
    int* srcidx = bsum + 256;                 // e
    float* dinv = (float*)(srcidx + e);       // n
    size_t off = (size_t)(3 * n + 1 + 256 + e + n);
    off = (off + 3) & ~(size_t)3;
    float* hs = (float*)d_ws + off;           // n*128
    float* h1 = hs + (size_t)n * 128;         // n*128
    float* ps2 = hs;                          // reuse (hs dead after gather1)

    int nbn = (n + 255) / 256;                // 196 (requires <=256 for scan2)
    int nbe = (e + 255) / 256;

    k_zero<<<nbn, 256, 0, stream>>>(cnt, n);
    k_hist<<<nbe, 256, 0, stream>>>(col, cnt, e);
    k_scan1<<<nbn, 256, 0, stream>>>(cnt, indptr, bsum, n);
    k_scan2<<<1, 256, 0, stream>>>(bsum, nbn);
    k_scan3<<<nbn, 256, 0, stream>>>(indptr, pos, bsum, cnt, dinv, n, e);
    k_scatter<<<nbe, 256, 0, stream>>>(row, col, pos, srcidx, e);

    k_gemm1<<<(n + 63) / 64, 256, 0, stream>>>(x, W1, dinv, hs, n);
    k_gather1<<<(n * 64 + 255) / 256, 256, 0, stream>>>(indptr, srcidx, hs, dinv, b1, h1, n);
    k_gemm2<<<(n + 63) / 64, 256, 0, stream>>>(h1, W2, dinv, ps2, n);
    k_gather2<<<(n * 64 + 255) / 256, 256, 0, stream>>>(indptr, srcidx, ps2, dinv, b2, out, n);
}

// Round 3
// 245.031 us; speedup vs baseline: 2.6075x; 1.2147x over previous
//
#include <hip/hip_runtime.h>

// ---------------------------------------------------------------------------
// GCN 2-layer: out = A_norm * relu(A_norm*(X@W1)+b1) @ W2 + b2
// A_norm = D^-1/2 (A + I) D^-1/2.
//
// Round-3: CSR-by-destination + gather-based segmented sums, with all
// intermediate node features (hs, h1, ps2) stored in bf16 to halve the
// random-gather traffic (the round-2 bottleneck: 225 MB L2-miss fetch in
// k_gather1). Accumulation is fp32; GEMM math is fp32 (VALU).
//   hs  = bf16( dinv * (X@W1) )                       [gemm1]
//   h1  = bf16( relu(dinv[c]*(hs[c]+sum hs[src])+b1) )  [gather1]
//   ps2 = bf16( dinv * (h1@W2) )                      [gemm2]
//   out = dinv[c]*(ps2[c]+sum ps2[src]) + b2  (fp32)  [gather2]
// ---------------------------------------------------------------------------

__device__ inline float bf2f(unsigned short u) {
    return __uint_as_float(((unsigned int)u) << 16);
}
__device__ inline unsigned short f2bf(float f) {
    unsigned int x = __float_as_uint(f);
    x = x + 0x7FFFu + ((x >> 16) & 1u);   // round-to-nearest-even
    return (unsigned short)(x >> 16);
}
__device__ inline float4 cvt4(ushort4 u) {
    return make_float4(bf2f(u.x), bf2f(u.y), bf2f(u.z), bf2f(u.w));
}

__global__ __launch_bounds__(256) void k_zero(int* __restrict__ cnt, int n) {
    int i = blockIdx.x * 256 + threadIdx.x;
    if (i < n) cnt[i] = 0;
}

__global__ __launch_bounds__(256) void k_hist(const int* __restrict__ col,
                                              int* __restrict__ cnt, int e) {
    int i = blockIdx.x * 256 + threadIdx.x;
    if (i < e) atomicAdd(&cnt[col[i]], 1);
}

__global__ __launch_bounds__(256) void k_scan1(const int* __restrict__ cnt,
                                               int* __restrict__ indptr,
                                               int* __restrict__ bsum, int n) {
    __shared__ int s[256];
    int t = threadIdx.x;
    int i = blockIdx.x * 256 + t;
    int v = (i < n) ? cnt[i] : 0;
    s[t] = v;
    __syncthreads();
#pragma unroll
    for (int off = 1; off < 256; off <<= 1) {
        int u = (t >= off) ? s[t - off] : 0;
        __syncthreads();
        s[t] += u;
        __syncthreads();
    }
    if (i < n) indptr[i] = s[t] - v;
    if (t == 255) bsum[blockIdx.x] = s[255];
}

__global__ __launch_bounds__(256) void k_scan2(int* __restrict__ bsum, int nb) {
    __shared__ int s[256];
    int t = threadIdx.x;
    int v = (t < nb) ? bsum[t] : 0;
    s[t] = v;
    __syncthreads();
#pragma unroll
    for (int off = 1; off < 256; off <<= 1) {
        int u = (t >= off) ? s[t - off] : 0;
        __syncthreads();
        s[t] += u;
        __syncthreads();
    }
    if (t < nb) bsum[t] = s[t] - v;
}

__global__ __launch_bounds__(256) void k_scan3(int* __restrict__ indptr,
                                               int* __restrict__ pos,
                                               const int* __restrict__ bsum,
                                               const int* __restrict__ cnt,
                                               float* __restrict__ dinv,
                                               int n, int e) {
    int i = blockIdx.x * 256 + threadIdx.x;
    if (i < n) {
        int v = indptr[i] + bsum[blockIdx.x];
        indptr[i] = v;
        pos[i] = v;
        dinv[i] = rsqrtf((float)cnt[i] + 1.0f);
        if (i == n - 1) indptr[n] = e;
    }
}

__global__ __launch_bounds__(256) void k_scatter(const int* __restrict__ row,
                                                 const int* __restrict__ col,
                                                 int* __restrict__ pos,
                                                 int* __restrict__ srcidx, int e) {
    int i = blockIdx.x * 256 + threadIdx.x;
    if (i < e) {
        int p = atomicAdd(&pos[col[i]], 1);
        srcidx[p] = row[i];
    }
}

// GEMM1: hs = bf16( dinv[i] * (X @ W1) ). X:[n,128] f32, W1:[128,128] f32.
__global__ __launch_bounds__(256) void k_gemm1(const float* __restrict__ x,
                                               const float* __restrict__ W,
                                               const float* __restrict__ dinv,
                                               unsigned short* __restrict__ hs, int n) {
    __shared__ float Ws[128 * 128];
    __shared__ float Xs[64 * 132];
    int t = threadIdx.x;

    const float4* Wv = (const float4*)W;
    float4* Wsv = (float4*)Ws;
#pragma unroll
    for (int i = 0; i < 16; ++i) Wsv[t + i * 256] = Wv[t + i * 256];

    int r0blk = blockIdx.x * 64;
    const float4* Xv = (const float4*)x;
#pragma unroll
    for (int i = 0; i < 8; ++i) {
        int idx = t + i * 256;
        int r = idx >> 5;
        int kq = idx & 31;
        float4 v = make_float4(0.f, 0.f, 0.f, 0.f);
        int gr = r0blk + r;
        if (gr < n) v = Xv[gr * 32 + kq];
        *(float4*)&Xs[r * 132 + kq * 4] = v;
    }
    __syncthreads();

    int tx = t & 15, ty = t >> 4;
    int j0 = tx * 8, r0 = ty * 4;
    float acc[4][8];
#pragma unroll
    for (int a = 0; a < 4; ++a)
#pragma unroll
        for (int b = 0; b < 8; ++b) acc[a][b] = 0.f;

#pragma unroll 4
    for (int k = 0; k < 128; ++k) {
        float xv[4];
#pragma unroll
        for (int a = 0; a < 4; ++a) xv[a] = Xs[(r0 + a) * 132 + k];
        float4 wa = *(const float4*)&Ws[k * 128 + j0];
        float4 wb = *(const float4*)&Ws[k * 128 + j0 + 4];
        float w[8] = {wa.x, wa.y, wa.z, wa.w, wb.x, wb.y, wb.z, wb.w};
#pragma unroll
        for (int a = 0; a < 4; ++a)
#pragma unroll
            for (int b = 0; b < 8; ++b) acc[a][b] += xv[a] * w[b];
    }

#pragma unroll
    for (int a = 0; a < 4; ++a) {
        int gr = r0blk + r0 + a;
        if (gr < n) {
            float d = dinv[gr];
            ushort4 o0, o1;
            o0.x = f2bf(acc[a][0] * d); o0.y = f2bf(acc[a][1] * d);
            o0.z = f2bf(acc[a][2] * d); o0.w = f2bf(acc[a][3] * d);
            o1.x = f2bf(acc[a][4] * d); o1.y = f2bf(acc[a][5] * d);
            o1.z = f2bf(acc[a][6] * d); o1.w = f2bf(acc[a][7] * d);
            *(ushort4*)&hs[gr * 128 + j0]     = o0;
            *(ushort4*)&hs[gr * 128 + j0 + 4] = o1;
        }
    }
}

// Gather1: one wave per node. Half-wave per edge: lanes 0-31 handle even
// edges, 32-63 odd edges; each lane covers 4 channels (ushort4, 8B).
// 8 edges in flight per unrolled iteration. Combine halves with shfl_xor(32).
__global__ __launch_bounds__(256) void k_gather1(const int* __restrict__ indptr,
                                                 const int* __restrict__ srcidx,
                                                 const unsigned short* __restrict__ hs,
                                                 const float* __restrict__ dinv,
                                                 const float* __restrict__ b1,
                                                 unsigned short* __restrict__ h1, int n) {
    int wid = (blockIdx.x * 256 + threadIdx.x) >> 6;
    if (wid >= n) return;
    int lane = threadIdx.x & 63;
    int half = lane >> 5;
    int hl = lane & 31;                      // channel quad: hl -> ch 4*hl..4*hl+3
    const ushort4* hv = (const ushort4*)hs;  // row stride 32 ushort4

    int beg = indptr[wid], end = indptr[wid + 1];
    float4 a0 = make_float4(0.f, 0.f, 0.f, 0.f), a1 = a0, a2 = a0, a3 = a0;

    int j = beg;
    for (; j + 7 < end; j += 8) {
        int sA = srcidx[j + half];
        int sB = srcidx[j + 2 + half];
        int sC = srcidx[j + 4 + half];
        int sD = srcidx[j + 6 + half];
        ushort4 uA = hv[sA * 32 + hl];
        ushort4 uB = hv[sB * 32 + hl];
        ushort4 uC = hv[sC * 32 + hl];
        ushort4 uD = hv[sD * 32 + hl];
        float4 v;
        v = cvt4(uA); a0.x += v.x; a0.y += v.y; a0.z += v.z; a0.w += v.w;
        v = cvt4(uB); a1.x += v.x; a1.y += v.y; a1.z += v.z; a1.w += v.w;
        v = cvt4(uC); a2.x += v.x; a2.y += v.y; a2.z += v.z; a2.w += v.w;
        v = cvt4(uD); a3.x += v.x; a3.y += v.y; a3.z += v.z; a3.w += v.w;
    }
    if (j + half < end) {
        float4 v = cvt4(hv[srcidx[j + half] * 32 + hl]);
        a0.x += v.x; a0.y += v.y; a0.z += v.z; a0.w += v.w;
    }
    j += 2;
    if (j + half < end) {
        float4 v = cvt4(hv[srcidx[j + half] * 32 + hl]);
        a1.x += v.x; a1.y += v.y; a1.z += v.z; a1.w += v.w;
    }
    j += 2;
    if (j + half < end) {
        float4 v = cvt4(hv[srcidx[j + half] * 32 + hl]);
        a2.x += v.x; a2.y += v.y; a2.z += v.z; a2.w += v.w;
    }
    j += 2;
    if (j + half < end) {
        float4 v = cvt4(hv[srcidx[j + half] * 32 + hl]);
        a3.x += v.x; a3.y += v.y; a3.z += v.z; a3.w += v.w;
    }

    // self-loop term (add once, in low half only)
    float4 sv = cvt4(hv[wid * 32 + hl]);
    if (half == 0) {
        a0.x += sv.x; a0.y += sv.y; a0.z += sv.z; a0.w += sv.w;
    }

    float4 tsum;
    tsum.x = a0.x + a1.x + a2.x + a3.x;
    tsum.y = a0.y + a1.y + a2.y + a3.y;
    tsum.z = a0.z + a1.z + a2.z + a3.z;
    tsum.w = a0.w + a1.w + a2.w + a3.w;
    tsum.x += __shfl_xor(tsum.x, 32);
    tsum.y += __shfl_xor(tsum.y, 32);
    tsum.z += __shfl_xor(tsum.z, 32);
    tsum.w += __shfl_xor(tsum.w, 32);

    if (half == 0) {
        float d = dinv[wid];
        float4 bb = *(const float4*)&b1[hl * 4];
        ushort4 o;
        o.x = f2bf(fmaxf(tsum.x * d + bb.x, 0.f));
        o.y = f2bf(fmaxf(tsum.y * d + bb.y, 0.f));
        o.z = f2bf(fmaxf(tsum.z * d + bb.z, 0.f));
        o.w = f2bf(fmaxf(tsum.w * d + bb.w, 0.f));
        ((ushort4*)h1)[wid * 32 + hl] = o;
    }
}

// GEMM2: ps2 = bf16( dinv[i] * (h1 @ W2) ). h1:[n,128] bf16, W2:[128,64] f32.
__global__ __launch_bounds__(256) void k_gemm2(const unsigned short* __restrict__ h1,
                                               const float* __restrict__ W2,
                                               const float* __restrict__ dinv,
                                               unsigned short* __restrict__ ps2, int n) {
    __shared__ float Ws[128 * 64];
    __shared__ float Xs[64 * 132];
    int t = threadIdx.x;

    const float4* Wv = (const float4*)W2;
    float4* Wsv = (float4*)Ws;
#pragma unroll
    for (int i = 0; i < 8; ++i) Wsv[t + i * 256] = Wv[t + i * 256];

    int r0blk = blockIdx.x * 64;
    const ushort4* Xv = (const ushort4*)h1;   // 32 per row
#pragma unroll
    for (int i = 0; i < 8; ++i) {
        int idx = t + i * 256;
        int r = idx >> 5;
        int kq = idx & 31;
        float4 v = make_float4(0.f, 0.f, 0.f, 0.f);
        int gr = r0blk + r;
        if (gr < n) v = cvt4(Xv[gr * 32 + kq]);
        *(float4*)&Xs[r * 132 + kq * 4] = v;
    }
    __syncthreads();

    int tx = t & 15, ty = t >> 4;
    int j0 = tx * 4, r0 = ty * 4;
    float acc[4][4];
#pragma unroll
    for (int a = 0; a < 4; ++a)
#pragma unroll
        for (int b = 0; b < 4; ++b) acc[a][b] = 0.f;

#pragma unroll 4
    for (int k = 0; k < 128; ++k) {
        float xv[4];
#pragma unroll
        for (int a = 0; a < 4; ++a) xv[a] = Xs[(r0 + a) * 132 + k];
        float4 w = *(const float4*)&Ws[k * 64 + j0];
#pragma unroll
        for (int a = 0; a < 4; ++a) {
            acc[a][0] += xv[a] * w.x;
            acc[a][1] += xv[a] * w.y;
            acc[a][2] += xv[a] * w.z;
            acc[a][3] += xv[a] * w.w;
        }
    }

#pragma unroll
    for (int a = 0; a < 4; ++a) {
        int gr = r0blk + r0 + a;
        if (gr < n) {
            float d = dinv[gr];
            ushort4 o;
            o.x = f2bf(acc[a][0] * d);
            o.y = f2bf(acc[a][1] * d);
            o.z = f2bf(acc[a][2] * d);
            o.w = f2bf(acc[a][3] * d);
            *(ushort4*)&ps2[gr * 64 + j0] = o;
        }
    }
}

// Gather2: one wave per node. Half-wave per edge, 2 channels/lane (uint, 4B).
__global__ __launch_bounds__(256) void k_gather2(const int* __restrict__ indptr,
                                                 const int* __restrict__ srcidx,
                                                 const unsigned short* __restrict__ ps2,
                                                 const float* __restrict__ dinv,
                                                 const float* __restrict__ b2,
                                                 float* __restrict__ out, int n) {
    int wid = (blockIdx.x * 256 + threadIdx.x) >> 6;
    if (wid >= n) return;
    int lane = threadIdx.x & 63;
    int half = lane >> 5;
    int hl = lane & 31;                         // channel pair: ch 2*hl, 2*hl+1
    const unsigned int* pv = (const unsigned int*)ps2;  // row stride 32 uints

    int beg = indptr[wid], end = indptr[wid + 1];
    float2 a0 = make_float2(0.f, 0.f), a1 = a0, a2 = a0, a3 = a0;

    int j = beg;
    for (; j + 7 < end; j += 8) {
        int sA = srcidx[j + half];
        int sB = srcidx[j + 2 + half];
        int sC = srcidx[j + 4 + half];
        int sD = srcidx[j + 6 + half];
        unsigned int uA = pv[sA * 32 + hl];
        unsigned int uB = pv[sB * 32 + hl];
        unsigned int uC = pv[sC * 32 + hl];
        unsigned int uD = pv[sD * 32 + hl];
        a0.x += bf2f((unsigned short)uA); a0.y += bf2f((unsigned short)(uA >> 16));
        a1.x += bf2f((unsigned short)uB); a1.y += bf2f((unsigned short)(uB >> 16));
        a2.x += bf2f((unsigned short)uC); a2.y += bf2f((unsigned short)(uC >> 16));
        a3.x += bf2f((unsigned short)uD); a3.y += bf2f((unsigned short)(uD >> 16));
    }
    if (j + half < end) {
        unsigned int u = pv[srcidx[j + half] * 32 + hl];
        a0.x += bf2f((unsigned short)u); a0.y += bf2f((unsigned short)(u >> 16));
    }
    j += 2;
    if (j + half < end) {
        unsigned int u = pv[srcidx[j + half] * 32 + hl];
        a1.x += bf2f((unsigned short)u); a1.y += bf2f((unsigned short)(u >> 16));
    }
    j += 2;
    if (j + half < end) {
        unsigned int u = pv[srcidx[j + half] * 32 + hl];
        a2.x += bf2f((unsigned short)u); a2.y += bf2f((unsigned short)(u >> 16));
    }
    j += 2;
    if (j + half < end) {
        unsigned int u = pv[srcidx[j + half] * 32 + hl];
        a3.x += bf2f((unsigned short)u); a3.y += bf2f((unsigned short)(u >> 16));
    }

    unsigned int us = pv[wid * 32 + hl];
    if (half == 0) {
        a0.x += bf2f((unsigned short)us); a0.y += bf2f((unsigned short)(us >> 16));
    }

    float2 tsum;
    tsum.x = a0.x + a1.x + a2.x + a3.x;
    tsum.y = a0.y + a1.y + a2.y + a3.y;
    tsum.x += __shfl_xor(tsum.x, 32);
    tsum.y += __shfl_xor(tsum.y, 32);

    if (half == 0) {
        float d = dinv[wid];
        float2 bb = *(const float2*)&b2[hl * 2];
        float2 o;
        o.x = tsum.x * d + bb.x;
        o.y = tsum.y * d + bb.y;
        ((float2*)out)[wid * 32 + hl] = o;
    }
}

extern "C" void kernel_launch(void* const* d_in, const int* in_sizes, int n_in,
                              void* d_out, int out_size, void* d_ws, size_t ws_size,
                              hipStream_t stream) {
    const float* x  = (const float*)d_in[0];
    const int*   ei = (const int*)d_in[1];
    const float* W1 = (const float*)d_in[2];
    const float* b1 = (const float*)d_in[3];
    const float* W2 = (const float*)d_in[4];
    const float* b2 = (const float*)d_in[5];
    float* out = (float*)d_out;

    int n = in_sizes[0] / 128;       // 50000
    int e = in_sizes[1] / 2;         // 800000
    const int* row = ei;             // sources
    const int* col = ei + e;         // destinations

    int* iw = (int*)d_ws;
    int* cnt    = iw;                         // n
    int* indptr = cnt + n;                    // n+1
    int* pos    = indptr + (n + 1);           // n
    int* bsum   = pos + n;                    // 256
    int* srcidx = bsum + 256;                 // e
    float* dinv = (float*)(srcidx + e);       // n
    size_t off = (size_t)(3 * n + 1 + 256 + e + n);
    off = (off + 3) & ~(size_t)3;             // 16B align
    unsigned short* hs = (unsigned short*)((float*)d_ws + off);  // n*128 bf16
    unsigned short* h1 = hs + (size_t)n * 128;                   // n*128 bf16
    unsigned short* ps2 = hs;                 // reuse (hs dead after gather1)

    int nbn = (n + 255) / 256;
    int nbe = (e + 255) / 256;

    k_zero<<<nbn, 256, 0, stream>>>(cnt, n);
    k_hist<<<nbe, 256, 0, stream>>>(col, cnt, e);
    k_scan1<<<nbn, 256, 0, stream>>>(cnt, indptr, bsum, n);
    k_scan2<<<1, 256, 0, stream>>>(bsum, nbn);
    k_scan3<<<nbn, 256, 0, stream>>>(indptr, pos, bsum, cnt, dinv, n, e);
    k_scatter<<<nbe, 256, 0, stream>>>(row, col, pos, srcidx, e);

    k_gemm1<<<(n + 63) / 64, 256, 0, stream>>>(x, W1, dinv, hs, n);
    k_gather1<<<(n * 64 + 255) / 256, 256, 0, stream>>>(indptr, srcidx, hs, dinv, b1, h1, n);
    k_gemm2<<<(n + 63) / 64, 256, 0, stream>>>(h1, W2, dinv, ps2, n);
    k_gather2<<<(n * 64 + 255) / 256, 256, 0, stream>>>(indptr, srcidx, ps2, dinv, b2, out, n);
}

// Round 4
// 189.741 us; speedup vs baseline: 3.3673x; 1.2914x over previous
//
#include <hip/hip_runtime.h>

// ---------------------------------------------------------------------------
// GCN 2-layer: out = A_norm * relu(A_norm*(X@W1)+b1) @ W2 + b2
// A_norm = D^-1/2 (A + I) D^-1/2.
//
// Round-4: MFMA-bf16 GEMMs (16x16x32), CSR-by-destination + bf16 gathers.
//   hs  = bf16( dinv * (X@W1) )                         [gemm1, MFMA]
//   h1  = bf16( relu(dinv[c]*(hs[c]+sum hs[src])+b1) )  [gather1]
//   ps2 = bf16( dinv * (h1@W2) )                        [gemm2, MFMA]
//   out = dinv[c]*(ps2[c]+sum ps2[src]) + b2  (fp32)    [gather2]
// ---------------------------------------------------------------------------

typedef float f32x4 __attribute__((ext_vector_type(4)));
typedef short bf16x8 __attribute__((ext_vector_type(8)));

__device__ inline float bf2f(unsigned short u) {
    return __uint_as_float(((unsigned int)u) << 16);
}
__device__ inline unsigned short f2bf(float f) {
    unsigned int x = __float_as_uint(f);
    x = x + 0x7FFFu + ((x >> 16) & 1u);   // round-to-nearest-even
    return (unsigned short)(x >> 16);
}
__device__ inline float4 cvt4(ushort4 u) {
    return make_float4(bf2f(u.x), bf2f(u.y), bf2f(u.z), bf2f(u.w));
}

__global__ __launch_bounds__(256) void k_zero(int* __restrict__ cnt, int n) {
    int i = blockIdx.x * 256 + threadIdx.x;
    if (i < n) cnt[i] = 0;
}

__global__ __launch_bounds__(256) void k_hist(const int* __restrict__ col,
                                              int* __restrict__ cnt, int e) {
    int i = blockIdx.x * 256 + threadIdx.x;
    if (i < e) atomicAdd(&cnt[col[i]], 1);
}

__global__ __launch_bounds__(256) void k_scan1(const int* __restrict__ cnt,
                                               int* __restrict__ indptr,
                                               int* __restrict__ bsum, int n) {
    __shared__ int s[256];
    int t = threadIdx.x;
    int i = blockIdx.x * 256 + t;
    int v = (i < n) ? cnt[i] : 0;
    s[t] = v;
    __syncthreads();
#pragma unroll
    for (int off = 1; off < 256; off <<= 1) {
        int u = (t >= off) ? s[t - off] : 0;
        __syncthreads();
        s[t] += u;
        __syncthreads();
    }
    if (i < n) indptr[i] = s[t] - v;
    if (t == 255) bsum[blockIdx.x] = s[255];
}

__global__ __launch_bounds__(256) void k_scan2(int* __restrict__ bsum, int nb) {
    __shared__ int s[256];
    int t = threadIdx.x;
    int v = (t < nb) ? bsum[t] : 0;
    s[t] = v;
    __syncthreads();
#pragma unroll
    for (int off = 1; off < 256; off <<= 1) {
        int u = (t >= off) ? s[t - off] : 0;
        __syncthreads();
        s[t] += u;
        __syncthreads();
    }
    if (t < nb) bsum[t] = s[t] - v;
}

__global__ __launch_bounds__(256) void k_scan3(int* __restrict__ indptr,
                                               int* __restrict__ pos,
                                               const int* __restrict__ bsum,
                                               const int* __restrict__ cnt,
                                               float* __restrict__ dinv,
                                               int n, int e) {
    int i = blockIdx.x * 256 + threadIdx.x;
    if (i < n) {
        int v = indptr[i] + bsum[blockIdx.x];
        indptr[i] = v;
        pos[i] = v;
        dinv[i] = rsqrtf((float)cnt[i] + 1.0f);
        if (i == n - 1) indptr[n] = e;
    }
}

__global__ __launch_bounds__(256) void k_scatter(const int* __restrict__ row,
                                                 const int* __restrict__ col,
                                                 int* __restrict__ pos,
                                                 unsigned short* __restrict__ srcidx, int e) {
    int i = blockIdx.x * 256 + threadIdx.x;
    if (i < e) {
        int p = atomicAdd(&pos[col[i]], 1);
        srcidx[p] = (unsigned short)row[i];
    }
}

// Transpose + convert weights to bf16: Wt1[nc][k] = W1[k][nc], Wt2[nc][k] = W2[k][nc].
__global__ __launch_bounds__(256) void k_prepw(const float* __restrict__ W1,
                                               const float* __restrict__ W2,
                                               unsigned short* __restrict__ Wt1,
                                               unsigned short* __restrict__ Wt2) {
    int i = blockIdx.x * 256 + threadIdx.x;
    if (i < 16384) {                       // W1: 128x128
        int k = i >> 7, nc = i & 127;
        Wt1[nc * 128 + k] = f2bf(W1[i]);
    } else if (i < 16384 + 8192) {         // W2: 128x64
        int i2 = i - 16384;
        int k = i2 >> 6, nc = i2 & 63;
        Wt2[nc * 128 + k] = f2bf(W2[i2]);
    }
}

// GEMM1 (MFMA): hs = bf16( dinv[i] * (X @ W1) ). Tile 128 rows x 128 cols, K=128.
// 4 waves; wave computes 32 rows x 128 cols = 2 Mfrag x 8 Nfrag of 16x16x32.
__global__ __launch_bounds__(256, 2) void k_gemm1(const float* __restrict__ x,
                                                  const unsigned short* __restrict__ Wt,
                                                  const float* __restrict__ dinv,
                                                  unsigned short* __restrict__ hs, int n) {
    __shared__ unsigned short Xs[128 * 136];
    __shared__ unsigned short Ws[128 * 136];
    __shared__ float dinv_s[128];
    int t = threadIdx.x;
    int r0blk = blockIdx.x * 128;

    // Stage Wt (bf16, already transposed): 2048 chunks of 8 bf16.
#pragma unroll
    for (int i = 0; i < 8; ++i) {
        int c = t + i * 256;
        int nc = c >> 4;
        int k0 = (c & 15) * 8;
        bf16x8 v = *(const bf16x8*)&Wt[nc * 128 + k0];
        *(bf16x8*)&Ws[nc * 136 + k0] = v;
    }
    // Stage X (fp32 -> bf16): 4096 float4 chunks.
#pragma unroll
    for (int i = 0; i < 16; ++i) {
        int c = t + i * 256;
        int r = c >> 5;
        int kq = c & 31;
        float4 v = make_float4(0.f, 0.f, 0.f, 0.f);
        int gr = r0blk + r;
        if (gr < n) v = ((const float4*)x)[gr * 32 + kq];
        ushort4 o;
        o.x = f2bf(v.x); o.y = f2bf(v.y); o.z = f2bf(v.z); o.w = f2bf(v.w);
        *(ushort4*)&Xs[r * 136 + kq * 4] = o;
    }
    if (t < 128) {
        int gr = r0blk + t;
        dinv_s[t] = (gr < n) ? dinv[gr] : 0.f;
    }
    __syncthreads();

    int lane = t & 63, wave = t >> 6;
    int lrow = lane & 15;
    int lk = (lane >> 4) * 8;

    f32x4 acc[2][8];
#pragma unroll
    for (int mi = 0; mi < 2; ++mi)
#pragma unroll
        for (int ni = 0; ni < 8; ++ni) acc[mi][ni] = (f32x4){0.f, 0.f, 0.f, 0.f};

#pragma unroll
    for (int ks = 0; ks < 4; ++ks) {
        int kk = ks * 32 + lk;
        bf16x8 a0 = *(bf16x8*)&Xs[(wave * 32 + lrow) * 136 + kk];
        bf16x8 a1 = *(bf16x8*)&Xs[(wave * 32 + 16 + lrow) * 136 + kk];
#pragma unroll
        for (int ni = 0; ni < 8; ++ni) {
            bf16x8 b = *(bf16x8*)&Ws[(ni * 16 + lrow) * 136 + kk];
            acc[0][ni] = __builtin_amdgcn_mfma_f32_16x16x32_bf16(a0, b, acc[0][ni], 0, 0, 0);
            acc[1][ni] = __builtin_amdgcn_mfma_f32_16x16x32_bf16(a1, b, acc[1][ni], 0, 0, 0);
        }
    }

    int rq = (lane >> 4) * 4;
#pragma unroll
    for (int mi = 0; mi < 2; ++mi)
#pragma unroll
        for (int r = 0; r < 4; ++r) {
            int lrw = wave * 32 + mi * 16 + rq + r;
            int grow = r0blk + lrw;
            if (grow < n) {
                float dv = dinv_s[lrw];
#pragma unroll
                for (int ni = 0; ni < 8; ++ni)
                    hs[grow * 128 + ni * 16 + lrow] = f2bf(acc[mi][ni][r] * dv);
            }
        }
}

// Gather1: one wave per node, half-wave per edge, ushort4 (4ch)/lane.
__global__ __launch_bounds__(256) void k_gather1(const int* __restrict__ indptr,
                                                 const unsigned short* __restrict__ srcidx,
                                                 const unsigned short* __restrict__ hs,
                                                 const float* __restrict__ dinv,
                                                 const float* __restrict__ b1,
                                                 unsigned short* __restrict__ h1, int n) {
    int wid = (blockIdx.x * 256 + threadIdx.x) >> 6;
    if (wid >= n) return;
    int lane = threadIdx.x & 63;
    int half = lane >> 5;
    int hl = lane & 31;
    const ushort4* hv = (const ushort4*)hs;

    int beg = indptr[wid], end = indptr[wid + 1];
    float4 a0 = make_float4(0.f, 0.f, 0.f, 0.f), a1 = a0, a2 = a0, a3 = a0;

    int j = beg;
    for (; j + 7 < end; j += 8) {
        int sA = srcidx[j + half];
        int sB = srcidx[j + 2 + half];
        int sC = srcidx[j + 4 + half];
        int sD = srcidx[j + 6 + half];
        float4 v;
        v = cvt4(hv[sA * 32 + hl]); a0.x += v.x; a0.y += v.y; a0.z += v.z; a0.w += v.w;
        v = cvt4(hv[sB * 32 + hl]); a1.x += v.x; a1.y += v.y; a1.z += v.z; a1.w += v.w;
        v = cvt4(hv[sC * 32 + hl]); a2.x += v.x; a2.y += v.y; a2.z += v.z; a2.w += v.w;
        v = cvt4(hv[sD * 32 + hl]); a3.x += v.x; a3.y += v.y; a3.z += v.z; a3.w += v.w;
    }
    if (j + half < end) {
        float4 v = cvt4(hv[srcidx[j + half] * 32 + hl]);
        a0.x += v.x; a0.y += v.y; a0.z += v.z; a0.w += v.w;
    }
    j += 2;
    if (j + half < end) {
        float4 v = cvt4(hv[srcidx[j + half] * 32 + hl]);
        a1.x += v.x; a1.y += v.y; a1.z += v.z; a1.w += v.w;
    }
    j += 2;
    if (j + half < end) {
        float4 v = cvt4(hv[srcidx[j + half] * 32 + hl]);
        a2.x += v.x; a2.y += v.y; a2.z += v.z; a2.w += v.w;
    }
    j += 2;
    if (j + half < end) {
        float4 v = cvt4(hv[srcidx[j + half] * 32 + hl]);
        a3.x += v.x; a3.y += v.y; a3.z += v.z; a3.w += v.w;
    }

    float4 sv = cvt4(hv[wid * 32 + hl]);
    if (half == 0) {
        a0.x += sv.x; a0.y += sv.y; a0.z += sv.z; a0.w += sv.w;
    }

    float4 tsum;
    tsum.x = a0.x + a1.x + a2.x + a3.x;
    tsum.y = a0.y + a1.y + a2.y + a3.y;
    tsum.z = a0.z + a1.z + a2.z + a3.z;
    tsum.w = a0.w + a1.w + a2.w + a3.w;
    tsum.x += __shfl_xor(tsum.x, 32);
    tsum.y += __shfl_xor(tsum.y, 32);
    tsum.z += __shfl_xor(tsum.z, 32);
    tsum.w += __shfl_xor(tsum.w, 32);

    if (half == 0) {
        float d = dinv[wid];
        float4 bb = *(const float4*)&b1[hl * 4];
        ushort4 o;
        o.x = f2bf(fmaxf(tsum.x * d + bb.x, 0.f));
        o.y = f2bf(fmaxf(tsum.y * d + bb.y, 0.f));
        o.z = f2bf(fmaxf(tsum.z * d + bb.z, 0.f));
        o.w = f2bf(fmaxf(tsum.w * d + bb.w, 0.f));
        ((ushort4*)h1)[wid * 32 + hl] = o;
    }
}

// GEMM2 (MFMA): ps2 = bf16( dinv[i] * (h1 @ W2) ). Tile 128x64, K=128.
// 4 waves; wave computes 32 rows x 64 cols = 2 Mfrag x 4 Nfrag.
__global__ __launch_bounds__(256, 3) void k_gemm2(const unsigned short* __restrict__ h1,
                                                  const unsigned short* __restrict__ Wt,
                                                  const float* __restrict__ dinv,
                                                  unsigned short* __restrict__ ps2, int n) {
    __shared__ unsigned short Xs[128 * 136];
    __shared__ unsigned short Ws[64 * 136];
    __shared__ float dinv_s[128];
    int t = threadIdx.x;
    int r0blk = blockIdx.x * 128;

    // Stage Wt2: 1024 chunks of 8 bf16.
#pragma unroll
    for (int i = 0; i < 4; ++i) {
        int c = t + i * 256;
        int nc = c >> 4;
        int k0 = (c & 15) * 8;
        bf16x8 v = *(const bf16x8*)&Wt[nc * 128 + k0];
        *(bf16x8*)&Ws[nc * 136 + k0] = v;
    }
    // Stage h1 (bf16 direct): 2048 chunks of 8 bf16.
#pragma unroll
    for (int i = 0; i < 8; ++i) {
        int c = t + i * 256;
        int r = c >> 4;
        int k0 = (c & 15) * 8;
        int gr = r0blk + r;
        bf16x8 v = (bf16x8)(short)0;
        if (gr < n) v = *(const bf16x8*)&h1[gr * 128 + k0];
        *(bf16x8*)&Xs[r * 136 + k0] = v;
    }
    if (t < 128) {
        int gr = r0blk + t;
        dinv_s[t] = (gr < n) ? dinv[gr] : 0.f;
    }
    __syncthreads();

    int lane = t & 63, wave = t >> 6;
    int lrow = lane & 15;
    int lk = (lane >> 4) * 8;

    f32x4 acc[2][4];
#pragma unroll
    for (int mi = 0; mi < 2; ++mi)
#pragma unroll
        for (int ni = 0; ni < 4; ++ni) acc[mi][ni] = (f32x4){0.f, 0.f, 0.f, 0.f};

#pragma unroll
    for (int ks = 0; ks < 4; ++ks) {
        int kk = ks * 32 + lk;
        bf16x8 a0 = *(bf16x8*)&Xs[(wave * 32 + lrow) * 136 + kk];
        bf16x8 a1 = *(bf16x8*)&Xs[(wave * 32 + 16 + lrow) * 136 + kk];
#pragma unroll
        for (int ni = 0; ni < 4; ++ni) {
            bf16x8 b = *(bf16x8*)&Ws[(ni * 16 + lrow) * 136 + kk];
            acc[0][ni] = __builtin_amdgcn_mfma_f32_16x16x32_bf16(a0, b, acc[0][ni], 0, 0, 0);
            acc[1][ni] = __builtin_amdgcn_mfma_f32_16x16x32_bf16(a1, b, acc[1][ni], 0, 0, 0);
        }
    }

    int rq = (lane >> 4) * 4;
#pragma unroll
    for (int mi = 0; mi < 2; ++mi)
#pragma unroll
        for (int r = 0; r < 4; ++r) {
            int lrw = wave * 32 + mi * 16 + rq + r;
            int grow = r0blk + lrw;
            if (grow < n) {
                float dv = dinv_s[lrw];
#pragma unroll
                for (int ni = 0; ni < 4; ++ni)
                    ps2[grow * 64 + ni * 16 + lrow] = f2bf(acc[mi][ni][r] * dv);
            }
        }
}

// Gather2: one wave per node, half-wave per edge, uint (2ch)/lane.
__global__ __launch_bounds__(256) void k_gather2(const int* __restrict__ indptr,
                                                 const unsigned short* __restrict__ srcidx,
                                                 const unsigned short* __restrict__ ps2,
                                                 const float* __restrict__ dinv,
                                                 const float* __restrict__ b2,
                                                 float* __restrict__ out, int n) {
    int wid = (blockIdx.x * 256 + threadIdx.x) >> 6;
    if (wid >= n) return;
    int lane = threadIdx.x & 63;
    int half = lane >> 5;
    int hl = lane & 31;
    const unsigned int* pv = (const unsigned int*)ps2;

    int beg = indptr[wid], end = indptr[wid + 1];
    float2 a0 = make_float2(0.f, 0.f), a1 = a0, a2 = a0, a3 = a0;

    int j = beg;
    for (; j + 7 < end; j += 8) {
        int sA = srcidx[j + half];
        int sB = srcidx[j + 2 + half];
        int sC = srcidx[j + 4 + half];
        int sD = srcidx[j + 6 + half];
        unsigned int uA = pv[sA * 32 + hl];
        unsigned int uB = pv[sB * 32 + hl];
        unsigned int uC = pv[sC * 32 + hl];
        unsigned int uD = pv[sD * 32 + hl];
        a0.x += bf2f((unsigned short)uA); a0.y += bf2f((unsigned short)(uA >> 16));
        a1.x += bf2f((unsigned short)uB); a1.y += bf2f((unsigned short)(uB >> 16));
        a2.x += bf2f((unsigned short)uC); a2.y += bf2f((unsigned short)(uC >> 16));
        a3.x += bf2f((unsigned short)uD); a3.y += bf2f((unsigned short)(uD >> 16));
    }
    if (j + half < end) {
        unsigned int u = pv[srcidx[j + half] * 32 + hl];
        a0.x += bf2f((unsigned short)u); a0.y += bf2f((unsigned short)(u >> 16));
    }
    j += 2;
    if (j + half < end) {
        unsigned int u = pv[srcidx[j + half] * 32 + hl];
        a1.x += bf2f((unsigned short)u); a1.y += bf2f((unsigned short)(u >> 16));
    }
    j += 2;
    if (j + half < end) {
        unsigned int u = pv[srcidx[j + half] * 32 + hl];
        a2.x += bf2f((unsigned short)u); a2.y += bf2f((unsigned short)(u >> 16));
    }
    j += 2;
    if (j + half < end) {
        unsigned int u = pv[srcidx[j + half] * 32 + hl];
        a3.x += bf2f((unsigned short)u); a3.y += bf2f((unsigned short)(u >> 16));
    }

    unsigned int us = pv[wid * 32 + hl];
    if (half == 0) {
        a0.x += bf2f((unsigned short)us); a0.y += bf2f((unsigned short)(us >> 16));
    }

    float2 tsum;
    tsum.x = a0.x + a1.x + a2.x + a3.x;
    tsum.y = a0.y + a1.y + a2.y + a3.y;
    tsum.x += __shfl_xor(tsum.x, 32);
    tsum.y += __shfl_xor(tsum.y, 32);

    if (half == 0) {
        float d = dinv[wid];
        float2 bb = *(const float2*)&b2[hl * 2];
        float2 o;
        o.x = tsum.x * d + bb.x;
        o.y = tsum.y * d + bb.y;
        ((float2*)out)[wid * 32 + hl] = o;
    }
}

extern "C" void kernel_launch(void* const* d_in, const int* in_sizes, int n_in,
                              void* d_out, int out_size, void* d_ws, size_t ws_size,
                              hipStream_t stream) {
    const float* x  = (const float*)d_in[0];
    const int*   ei = (const int*)d_in[1];
    const float* W1 = (const float*)d_in[2];
    const float* b1 = (const float*)d_in[3];
    const float* W2 = (const float*)d_in[4];
    const float* b2 = (const float*)d_in[5];
    float* out = (float*)d_out;

    int n = in_sizes[0] / 128;       // 50000
    int e = in_sizes[1] / 2;         // 800000
    const int* row = ei;             // sources
    const int* col = ei + e;         // destinations

    // Workspace layout (in int units; 16B-aligned sections).
    int* iw = (int*)d_ws;
    int* cnt    = iw;                               // n
    int* indptr = cnt + n;                          // n+1
    int* pos    = indptr + (n + 1);                 // n
    int* bsum   = pos + n;                          // 256
    float* dinv = (float*)(bsum + 256);             // n
    size_t o = (size_t)(4 * n + 1 + 256);
    o = (o + 3) & ~(size_t)3;
    unsigned short* srcidx = (unsigned short*)(iw + o);  // e ushorts = e/2 ints
    o += (size_t)e / 2;
    o = (o + 3) & ~(size_t)3;
    unsigned short* Wt1 = (unsigned short*)(iw + o);     // 16384 ushorts
    o += 8192;
    unsigned short* Wt2 = (unsigned short*)(iw + o);     // 8192 ushorts
    o += 4096;
    unsigned short* hs = (unsigned short*)(iw + o);      // n*128 bf16
    unsigned short* h1 = hs + (size_t)n * 128;           // n*128 bf16
    unsigned short* ps2 = hs;                            // reuse after gather1

    int nbn = (n + 255) / 256;
    int nbe = (e + 255) / 256;
    int nbg = (n + 127) / 128;   // 391 gemm blocks

    k_zero<<<nbn, 256, 0, stream>>>(cnt, n);
    k_hist<<<nbe, 256, 0, stream>>>(col, cnt, e);
    k_scan1<<<nbn, 256, 0, stream>>>(cnt, indptr, bsum, n);
    k_scan2<<<1, 256, 0, stream>>>(bsum, nbn);
    k_scan3<<<nbn, 256, 0, stream>>>(indptr, pos, bsum, cnt, dinv, n, e);
    k_scatter<<<nbe, 256, 0, stream>>>(row, col, pos, srcidx, e);
    k_prepw<<<96, 256, 0, stream>>>(W1, W2, Wt1, Wt2);

    k_gemm1<<<nbg, 256, 0, stream>>>(x, Wt1, dinv, hs, n);
    k_gather1<<<(n * 64 + 255) / 256, 256, 0, stream>>>(indptr, srcidx, hs, dinv, b1, h1, n);
    k_gemm2<<<nbg, 256, 0, stream>>>(h1, Wt2, dinv, ps2, n);
    k_gather2<<<(n * 64 + 255) / 256, 256, 0, stream>>>(indptr, srcidx, ps2, dinv, b2, out, n);
}

// Round 5
// 136.090 us; speedup vs baseline: 4.6948x; 1.3942x over previous
//
#include <hip/hip_runtime.h>

// ---------------------------------------------------------------------------
// GCN 2-layer: out = A_norm * relu(A_norm*(X@W1)+b1) @ W2 + b2
// A_norm = D^-1/2 (A + I) D^-1/2.
//
// Round-5: CSR build via 2-pass MSD bucket sort (no global position atomics,
// block-owned write regions -> no cross-XCD line ping-pong). MFMA-bf16 GEMMs,
// bf16 gather-based segmented sums.
//   hs  = bf16( dinv * (X@W1) )                         [gemm1, MFMA]
//   h1  = bf16( relu(dinv[c]*(hs[c]+sum hs[src])+b1) )  [gather1]
//   ps2 = bf16( dinv * (h1@W2) )                        [gemm2, MFMA]
//   out = dinv[c]*(ps2[c]+sum ps2[src]) + b2  (fp32)    [gather2]
// ---------------------------------------------------------------------------

typedef float f32x4 __attribute__((ext_vector_type(4)));
typedef short bf16x8 __attribute__((ext_vector_type(8)));

#define EPB 4096   // edges per block in radix pass 1

__device__ inline float bf2f(unsigned short u) {
    return __uint_as_float(((unsigned int)u) << 16);
}
__device__ inline unsigned short f2bf(float f) {
    unsigned int x = __float_as_uint(f);
    x = x + 0x7FFFu + ((x >> 16) & 1u);   // round-to-nearest-even
    return (unsigned short)(x >> 16);
}
__device__ inline float4 cvt4(ushort4 u) {
    return make_float4(bf2f(u.x), bf2f(u.y), bf2f(u.z), bf2f(u.w));
}

// ---- CSR build: pass 1 histogram (bins = col>>8, bin-major layout) ----
__global__ __launch_bounds__(256) void k_rhist(const int* __restrict__ col,
                                               int* __restrict__ hist,
                                               int e, int nbR, int nbB) {
    __shared__ int h[256];
    int t = threadIdx.x;
    h[t] = 0;
    __syncthreads();
    int base = blockIdx.x * EPB;
#pragma unroll
    for (int i = 0; i < EPB / 256; ++i) {
        int idx = base + t + i * 256;
        if (idx < e) atomicAdd(&h[col[idx] >> 8], 1);
    }
    __syncthreads();
    if (t < nbB) hist[t * nbR + blockIdx.x] = h[t];
}

// Generic 2-level exclusive scan (m <= 65536).
__global__ __launch_bounds__(256) void k_scan1g(const int* __restrict__ src,
                                                int* __restrict__ dst,
                                                int* __restrict__ bsum, int m) {
    __shared__ int s[256];
    int t = threadIdx.x;
    int i = blockIdx.x * 256 + t;
    int v = (i < m) ? src[i] : 0;
    s[t] = v;
    __syncthreads();
#pragma unroll
    for (int off = 1; off < 256; off <<= 1) {
        int u = (t >= off) ? s[t - off] : 0;
        __syncthreads();
        s[t] += u;
        __syncthreads();
    }
    if (i < m) dst[i] = s[t] - v;
    if (t == 255) bsum[blockIdx.x] = s[255];
}

__global__ __launch_bounds__(256) void k_scan2(int* __restrict__ bsum, int nb) {
    __shared__ int s[256];
    int t = threadIdx.x;
    int v = (t < nb) ? bsum[t] : 0;
    s[t] = v;
    __syncthreads();
#pragma unroll
    for (int off = 1; off < 256; off <<= 1) {
        int u = (t >= off) ? s[t - off] : 0;
        __syncthreads();
        s[t] += u;
        __syncthreads();
    }
    if (t < nb) bsum[t] = s[t] - v;
}

__global__ __launch_bounds__(256) void k_scanaddg(int* __restrict__ dst,
                                                  const int* __restrict__ bsum, int m) {
    int i = blockIdx.x * 256 + threadIdx.x;
    if (i < m) dst[i] += bsum[blockIdx.x];
}

// ---- CSR build: pass 1 scatter into bucket-grouped tmp (block-owned runs) ----
__global__ __launch_bounds__(256) void k_rscatter(const int* __restrict__ row,
                                                  const int* __restrict__ col,
                                                  const int* __restrict__ histscan,
                                                  unsigned int* __restrict__ tmp,
                                                  int e, int nbR, int nbB) {
    __shared__ int base[256];
    __shared__ int h[256];
    int t = threadIdx.x;
    base[t] = (t < nbB) ? histscan[t * nbR + blockIdx.x] : 0;
    h[t] = 0;
    __syncthreads();
    int b0 = blockIdx.x * EPB;
#pragma unroll
    for (int i = 0; i < EPB / 256; ++i) {
        int idx = b0 + t + i * 256;
        if (idx < e) {
            int c = col[idx];
            int bin = c >> 8;
            int rk = atomicAdd(&h[bin], 1);
            tmp[base[bin] + rk] =
                ((unsigned int)(c & 255) << 16) | (unsigned int)row[idx];
        }
    }
}

// ---- CSR build: pass 2 per-bucket counting sort; emits indptr, dinv, srcidx ----
__global__ __launch_bounds__(256) void k_bsort(const unsigned int* __restrict__ tmp,
                                               const int* __restrict__ histscan,
                                               int* __restrict__ indptr,
                                               float* __restrict__ dinv,
                                               unsigned short* __restrict__ srcidx,
                                               int n, int e, int nbR, int nbB) {
    __shared__ int cnt[256];
    __shared__ int pre[256];
    int b = blockIdx.x;
    int t = threadIdx.x;
    int beg = histscan[b * nbR];
    int end = (b + 1 < nbB) ? histscan[(b + 1) * nbR] : e;

    cnt[t] = 0;
    __syncthreads();
    // phase A: count low-byte bins
    for (int i = beg + t; i < end; i += 256) atomicAdd(&cnt[tmp[i] >> 16], 1);
    __syncthreads();
    // phase B: exclusive scan of 256 counters
    int v = cnt[t];
    pre[t] = v;
    __syncthreads();
#pragma unroll
    for (int off = 1; off < 256; off <<= 1) {
        int u = (t >= off) ? pre[t - off] : 0;
        __syncthreads();
        pre[t] += u;
        __syncthreads();
    }
    int myexcl = pre[t] - v;
    int node = b * 256 + t;
    if (node < n) {
        indptr[node] = beg + myexcl;
        dinv[node] = rsqrtf((float)v + 1.0f);
    }
    if (b == nbB - 1 && t == 0) indptr[n] = e;
    __syncthreads();
    pre[t] = beg + myexcl;   // per-col output base
    cnt[t] = 0;              // rank counters
    __syncthreads();
    // phase C: scatter rows into this bucket's private srcidx window
    for (int i = beg + t; i < end; i += 256) {
        unsigned int u = tmp[i];
        int cl = u >> 16;
        int rk = atomicAdd(&cnt[cl], 1);
        srcidx[pre[cl] + rk] = (unsigned short)(u & 0xFFFFu);
    }
}

// Transpose + convert weights to bf16: Wt1[nc][k] = W1[k][nc], Wt2[nc][k] = W2[k][nc].
__global__ __launch_bounds__(256) void k_prepw(const float* __restrict__ W1,
                                               const float* __restrict__ W2,
                                               unsigned short* __restrict__ Wt1,
                                               unsigned short* __restrict__ Wt2) {
    int i = blockIdx.x * 256 + threadIdx.x;
    if (i < 16384) {                       // W1: 128x128
        int k = i >> 7, nc = i & 127;
        Wt1[nc * 128 + k] = f2bf(W1[i]);
    } else if (i < 16384 + 8192) {         // W2: 128x64
        int i2 = i - 16384;
        int k = i2 >> 6, nc = i2 & 63;
        Wt2[nc * 128 + k] = f2bf(W2[i2]);
    }
}

// GEMM1 (MFMA): hs = bf16( dinv[i] * (X @ W1) ). Tile 128x128, K=128.
__global__ __launch_bounds__(256, 2) void k_gemm1(const float* __restrict__ x,
                                                  const unsigned short* __restrict__ Wt,
                                                  const float* __restrict__ dinv,
                                                  unsigned short* __restrict__ hs, int n) {
    __shared__ unsigned short Xs[128 * 136];
    __shared__ unsigned short Ws[128 * 136];
    __shared__ float dinv_s[128];
    int t = threadIdx.x;
    int r0blk = blockIdx.x * 128;

#pragma unroll
    for (int i = 0; i < 8; ++i) {
        int c = t + i * 256;
        int nc = c >> 4;
        int k0 = (c & 15) * 8;
        bf16x8 v = *(const bf16x8*)&Wt[nc * 128 + k0];
        *(bf16x8*)&Ws[nc * 136 + k0] = v;
    }
#pragma unroll
    for (int i = 0; i < 16; ++i) {
        int c = t + i * 256;
        int r = c >> 5;
        int kq = c & 31;
        float4 v = make_float4(0.f, 0.f, 0.f, 0.f);
        int gr = r0blk + r;
        if (gr < n) v = ((const float4*)x)[gr * 32 + kq];
        ushort4 o;
        o.x = f2bf(v.x); o.y = f2bf(v.y); o.z = f2bf(v.z); o.w = f2bf(v.w);
        *(ushort4*)&Xs[r * 136 + kq * 4] = o;
    }
    if (t < 128) {
        int gr = r0blk + t;
        dinv_s[t] = (gr < n) ? dinv[gr] : 0.f;
    }
    __syncthreads();

    int lane = t & 63, wave = t >> 6;
    int lrow = lane & 15;
    int lk = (lane >> 4) * 8;

    f32x4 acc[2][8];
#pragma unroll
    for (int mi = 0; mi < 2; ++mi)
#pragma unroll
        for (int ni = 0; ni < 8; ++ni) acc[mi][ni] = (f32x4){0.f, 0.f, 0.f, 0.f};

#pragma unroll
    for (int ks = 0; ks < 4; ++ks) {
        int kk = ks * 32 + lk;
        bf16x8 a0 = *(bf16x8*)&Xs[(wave * 32 + lrow) * 136 + kk];
        bf16x8 a1 = *(bf16x8*)&Xs[(wave * 32 + 16 + lrow) * 136 + kk];
#pragma unroll
        for (int ni = 0; ni < 8; ++ni) {
            bf16x8 b = *(bf16x8*)&Ws[(ni * 16 + lrow) * 136 + kk];
            acc[0][ni] = __builtin_amdgcn_mfma_f32_16x16x32_bf16(a0, b, acc[0][ni], 0, 0, 0);
            acc[1][ni] = __builtin_amdgcn_mfma_f32_16x16x32_bf16(a1, b, acc[1][ni], 0, 0, 0);
        }
    }

    int rq = (lane >> 4) * 4;
#pragma unroll
    for (int mi = 0; mi < 2; ++mi)
#pragma unroll
        for (int r = 0; r < 4; ++r) {
            int lrw = wave * 32 + mi * 16 + rq + r;
            int grow = r0blk + lrw;
            if (grow < n) {
                float dv = dinv_s[lrw];
#pragma unroll
                for (int ni = 0; ni < 8; ++ni)
                    hs[grow * 128 + ni * 16 + lrow] = f2bf(acc[mi][ni][r] * dv);
            }
        }
}

// Gather1: one wave per node, half-wave per edge, ushort4 (4ch)/lane.
__global__ __launch_bounds__(256) void k_gather1(const int* __restrict__ indptr,
                                                 const unsigned short* __restrict__ srcidx,
                                                 const unsigned short* __restrict__ hs,
                                                 const float* __restrict__ dinv,
                                                 const float* __restrict__ b1,
                                                 unsigned short* __restrict__ h1, int n) {
    int wid = (blockIdx.x * 256 + threadIdx.x) >> 6;
    if (wid >= n) return;
    int lane = threadIdx.x & 63;
    int half = lane >> 5;
    int hl = lane & 31;
    const ushort4* hv = (const ushort4*)hs;

    int beg = indptr[wid], end = indptr[wid + 1];
    float4 a0 = make_float4(0.f, 0.f, 0.f, 0.f), a1 = a0, a2 = a0, a3 = a0;

    int j = beg;
    for (; j + 7 < end; j += 8) {
        int sA = srcidx[j + half];
        int sB = srcidx[j + 2 + half];
        int sC = srcidx[j + 4 + half];
        int sD = srcidx[j + 6 + half];
        float4 v;
        v = cvt4(hv[sA * 32 + hl]); a0.x += v.x; a0.y += v.y; a0.z += v.z; a0.w += v.w;
        v = cvt4(hv[sB * 32 + hl]); a1.x += v.x; a1.y += v.y; a1.z += v.z; a1.w += v.w;
        v = cvt4(hv[sC * 32 + hl]); a2.x += v.x; a2.y += v.y; a2.z += v.z; a2.w += v.w;
        v = cvt4(hv[sD * 32 + hl]); a3.x += v.x; a3.y += v.y; a3.z += v.z; a3.w += v.w;
    }
    if (j + half < end) {
        float4 v = cvt4(hv[srcidx[j + half] * 32 + hl]);
        a0.x += v.x; a0.y += v.y; a0.z += v.z; a0.w += v.w;
    }
    j += 2;
    if (j + half < end) {
        float4 v = cvt4(hv[srcidx[j + half] * 32 + hl]);
        a1.x += v.x; a1.y += v.y; a1.z += v.z; a1.w += v.w;
    }
    j += 2;
    if (j + half < end) {
        float4 v = cvt4(hv[srcidx[j + half] * 32 + hl]);
        a2.x += v.x; a2.y += v.y; a2.z += v.z; a2.w += v.w;
    }
    j += 2;
    if (j + half < end) {
        float4 v = cvt4(hv[srcidx[j + half] * 32 + hl]);
        a3.x += v.x; a3.y += v.y; a3.z += v.z; a3.w += v.w;
    }

    float4 sv = cvt4(hv[wid * 32 + hl]);
    if (half == 0) {
        a0.x += sv.x; a0.y += sv.y; a0.z += sv.z; a0.w += sv.w;
    }

    float4 tsum;
    tsum.x = a0.x + a1.x + a2.x + a3.x;
    tsum.y = a0.y + a1.y + a2.y + a3.y;
    tsum.z = a0.z + a1.z + a2.z + a3.z;
    tsum.w = a0.w + a1.w + a2.w + a3.w;
    tsum.x += __shfl_xor(tsum.x, 32);
    tsum.y += __shfl_xor(tsum.y, 32);
    tsum.z += __shfl_xor(tsum.z, 32);
    tsum.w += __shfl_xor(tsum.w, 32);

    if (half == 0) {
        float d = dinv[wid];
        float4 bb = *(const float4*)&b1[hl * 4];
        ushort4 o;
        o.x = f2bf(fmaxf(tsum.x * d + bb.x, 0.f));
        o.y = f2bf(fmaxf(tsum.y * d + bb.y, 0.f));
        o.z = f2bf(fmaxf(tsum.z * d + bb.z, 0.f));
        o.w = f2bf(fmaxf(tsum.w * d + bb.w, 0.f));
        ((ushort4*)h1)[wid * 32 + hl] = o;
    }
}

// GEMM2 (MFMA): ps2 = bf16( dinv[i] * (h1 @ W2) ). Tile 128x64, K=128.
__global__ __launch_bounds__(256, 3) void k_gemm2(const unsigned short* __restrict__ h1,
                                                  const unsigned short* __restrict__ Wt,
                                                  const float* __restrict__ dinv,
                                                  unsigned short* __restrict__ ps2, int n) {
    __shared__ unsigned short Xs[128 * 136];
    __shared__ unsigned short Ws[64 * 136];
    __shared__ float dinv_s[128];
    int t = threadIdx.x;
    int r0blk = blockIdx.x * 128;

#pragma unroll
    for (int i = 0; i < 4; ++i) {
        int c = t + i * 256;
        int nc = c >> 4;
        int k0 = (c & 15) * 8;
        bf16x8 v = *(const bf16x8*)&Wt[nc * 128 + k0];
        *(bf16x8*)&Ws[nc * 136 + k0] = v;
    }
#pragma unroll
    for (int i = 0; i < 8; ++i) {
        int c = t + i * 256;
        int r = c >> 4;
        int k0 = (c & 15) * 8;
        int gr = r0blk + r;
        bf16x8 v = (bf16x8)(short)0;
        if (gr < n) v = *(const bf16x8*)&h1[gr * 128 + k0];
        *(bf16x8*)&Xs[r * 136 + k0] = v;
    }
    if (t < 128) {
        int gr = r0blk + t;
        dinv_s[t] = (gr < n) ? dinv[gr] : 0.f;
    }
    __syncthreads();

    int lane = t & 63, wave = t >> 6;
    int lrow = lane & 15;
    int lk = (lane >> 4) * 8;

    f32x4 acc[2][4];
#pragma unroll
    for (int mi = 0; mi < 2; ++mi)
#pragma unroll
        for (int ni = 0; ni < 4; ++ni) acc[mi][ni] = (f32x4){0.f, 0.f, 0.f, 0.f};

#pragma unroll
    for (int ks = 0; ks < 4; ++ks) {
        int kk = ks * 32 + lk;
        bf16x8 a0 = *(bf16x8*)&Xs[(wave * 32 + lrow) * 136 + kk];
        bf16x8 a1 = *(bf16x8*)&Xs[(wave * 32 + 16 + lrow) * 136 + kk];
#pragma unroll
        for (int ni = 0; ni < 4; ++ni) {
            bf16x8 b = *(bf16x8*)&Ws[(ni * 16 + lrow) * 136 + kk];
            acc[0][ni] = __builtin_amdgcn_mfma_f32_16x16x32_bf16(a0, b, acc[0][ni], 0, 0, 0);
            acc[1][ni] = __builtin_amdgcn_mfma_f32_16x16x32_bf16(a1, b, acc[1][ni], 0, 0, 0);
        }
    }

    int rq = (lane >> 4) * 4;
#pragma unroll
    for (int mi = 0; mi < 2; ++mi)
#pragma unroll
        for (int r = 0; r < 4; ++r) {
            int lrw = wave * 32 + mi * 16 + rq + r;
            int grow = r0blk + lrw;
            if (grow < n) {
                float dv = dinv_s[lrw];
#pragma unroll
                for (int ni = 0; ni < 4; ++ni)
                    ps2[grow * 64 + ni * 16 + lrow] = f2bf(acc[mi][ni][r] * dv);
            }
        }
}

// Gather2: one wave per node, half-wave per edge, uint (2ch)/lane.
__global__ __launch_bounds__(256) void k_gather2(const int* __restrict__ indptr,
                                                 const unsigned short* __restrict__ srcidx,
                                                 const unsigned short* __restrict__ ps2,
                                                 const float* __restrict__ dinv,
                                                 const float* __restrict__ b2,
                                                 float* __restrict__ out, int n) {
    int wid = (blockIdx.x * 256 + threadIdx.x) >> 6;
    if (wid >= n) return;
    int lane = threadIdx.x & 63;
    int half = lane >> 5;
    int hl = lane & 31;
    const unsigned int* pv = (const unsigned int*)ps2;

    int beg = indptr[wid], end = indptr[wid + 1];
    float2 a0 = make_float2(0.f, 0.f), a1 = a0, a2 = a0, a3 = a0;

    int j = beg;
    for (; j + 7 < end; j += 8) {
        int sA = srcidx[j + half];
        int sB = srcidx[j + 2 + half];
        int sC = srcidx[j + 4 + half];
        int sD = srcidx[j + 6 + half];
        unsigned int uA = pv[sA * 32 + hl];
        unsigned int uB = pv[sB * 32 + hl];
        unsigned int uC = pv[sC * 32 + hl];
        unsigned int uD = pv[sD * 32 + hl];
        a0.x += bf2f((unsigned short)uA); a0.y += bf2f((unsigned short)(uA >> 16));
        a1.x += bf2f((unsigned short)uB); a1.y += bf2f((unsigned short)(uB >> 16));
        a2.x += bf2f((unsigned short)uC); a2.y += bf2f((unsigned short)(uC >> 16));
        a3.x += bf2f((unsigned short)uD); a3.y += bf2f((unsigned short)(uD >> 16));
    }
    if (j + half < end) {
        unsigned int u = pv[srcidx[j + half] * 32 + hl];
        a0.x += bf2f((unsigned short)u); a0.y += bf2f((unsigned short)(u >> 16));
    }
    j += 2;
    if (j + half < end) {
        unsigned int u = pv[srcidx[j + half] * 32 + hl];
        a1.x += bf2f((unsigned short)u); a1.y += bf2f((unsigned short)(u >> 16));
    }
    j += 2;
    if (j + half < end) {
        unsigned int u = pv[srcidx[j + half] * 32 + hl];
        a2.x += bf2f((unsigned short)u); a2.y += bf2f((unsigned short)(u >> 16));
    }
    j += 2;
    if (j + half < end) {
        unsigned int u = pv[srcidx[j + half] * 32 + hl];
        a3.x += bf2f((unsigned short)u); a3.y += bf2f((unsigned short)(u >> 16));
    }

    unsigned int us = pv[wid * 32 + hl];
    if (half == 0) {
        a0.x += bf2f((unsigned short)us); a0.y += bf2f((unsigned short)(us >> 16));
    }

    float2 tsum;
    tsum.x = a0.x + a1.x + a2.x + a3.x;
    tsum.y = a0.y + a1.y + a2.y + a3.y;
    tsum.x += __shfl_xor(tsum.x, 32);
    tsum.y += __shfl_xor(tsum.y, 32);

    if (half == 0) {
        float d = dinv[wid];
        float2 bb = *(const float2*)&b2[hl * 2];
        float2 o;
        o.x = tsum.x * d + bb.x;
        o.y = tsum.y * d + bb.y;
        ((float2*)out)[wid * 32 + hl] = o;
    }
}

extern "C" void kernel_launch(void* const* d_in, const int* in_sizes, int n_in,
                              void* d_out, int out_size, void* d_ws, size_t ws_size,
                              hipStream_t stream) {
    const float* x  = (const float*)d_in[0];
    const int*   ei = (const int*)d_in[1];
    const float* W1 = (const float*)d_in[2];
    const float* b1 = (const float*)d_in[3];
    const float* W2 = (const float*)d_in[4];
    const float* b2 = (const float*)d_in[5];
    float* out = (float*)d_out;

    int n = in_sizes[0] / 128;       // 50000
    int e = in_sizes[1] / 2;         // 800000
    const int* row = ei;             // sources
    const int* col = ei + e;         // destinations

    int nbR = (e + EPB - 1) / EPB;   // 196 pass-1 blocks
    int nbB = (n + 255) / 256;       // 196 buckets
    int m   = nbB * nbR;             // 38416 hist entries (<= 65536)

    // Workspace layout (int units; 16B-aligned sections).
    int* iw = (int*)d_ws;
    size_t o = 0;
    int* hist     = iw + o; o += (size_t)m;        o = (o + 3) & ~(size_t)3;
    int* histscan = iw + o; o += (size_t)m;        o = (o + 3) & ~(size_t)3;
    int* bsum     = iw + o; o += 256;
    int* indptr   = iw + o; o += (size_t)(n + 1);  o = (o + 3) & ~(size_t)3;
    float* dinv   = (float*)(iw + o); o += (size_t)n; o = (o + 3) & ~(size_t)3;
    unsigned int* tmp = (unsigned int*)(iw + o); o += (size_t)e; o = (o + 3) & ~(size_t)3;
    unsigned short* srcidx = (unsigned short*)(iw + o); o += (size_t)(e / 2 + 2); o = (o + 3) & ~(size_t)3;
    unsigned short* Wt1 = (unsigned short*)(iw + o); o += 8192;
    unsigned short* Wt2 = (unsigned short*)(iw + o); o += 4096;
    unsigned short* hs  = (unsigned short*)(iw + o); // n*128 bf16 = n*64 ints
    unsigned short* h1  = hs + (size_t)n * 128;
    unsigned short* ps2 = hs;                        // reuse after gather1

    int nbm = (m + 255) / 256;       // 151 (<= 256 for k_scan2)

    k_rhist<<<nbR, 256, 0, stream>>>(col, hist, e, nbR, nbB);
    k_scan1g<<<nbm, 256, 0, stream>>>(hist, histscan, bsum, m);
    k_scan2<<<1, 256, 0, stream>>>(bsum, nbm);
    k_scanaddg<<<nbm, 256, 0, stream>>>(histscan, bsum, m);
    k_rscatter<<<nbR, 256, 0, stream>>>(row, col, histscan, tmp, e, nbR, nbB);
    k_bsort<<<nbB, 256, 0, stream>>>(tmp, histscan, indptr, dinv, srcidx, n, e, nbR, nbB);
    k_prepw<<<96, 256, 0, stream>>>(W1, W2, Wt1, Wt2);

    int nbg = (n + 127) / 128;
    k_gemm1<<<nbg, 256, 0, stream>>>(x, Wt1, dinv, hs, n);
    k_gather1<<<(n * 64 + 255) / 256, 256, 0, stream>>>(indptr, srcidx, hs, dinv, b1, h1, n);
    k_gemm2<<<nbg, 256, 0, stream>>>(h1, Wt2, dinv, ps2, n);
    k_gather2<<<(n * 64 + 255) / 256, 256, 0, stream>>>(indptr, srcidx, ps2, dinv, b2, out, n);
}